// Round 5
// baseline (1386.833 us; speedup 1.0000x reference)
//
#include <hip/hip_runtime.h>
#include <cstdint>
#include <cstddef>

// CIN: B=1024, M=40, D=64, HK=128. rows = B*D = 65536 (row = b*64 + d)
// y[r,h] = sum_i x0[r,i] * ( sum_j xk[r,j] * W[i,j,h] )
// Inner j-contraction via bf16 MFMA (xk split hi/lo once per layer in LDS);
// x0 applied per (i,jb) PARTIAL in exact f32 (linearity) -> no cross-jb t regs.
// 3-term split: xk*w ~= xkh*wh + xkh*wl + xkl*wh  (error ~2^-18 rel)

typedef __attribute__((ext_vector_type(4))) float f4v;
typedef __attribute__((ext_vector_type(8))) short s8v;

__device__ __forceinline__ unsigned short f2bf(float f){
  unsigned u = __float_as_uint(f);
  u += 0x7fffu + ((u >> 16) & 1u);      // RNE on bf16 boundary
  return (unsigned short)(u >> 16);
}

// ---------------- weight prep: split + transpose into ws ----------------
// ws layout (ushort units):
//  W0hi @ 0        [128][2560]   (k = i*64 + j, j<40 real else 0)
//  W0lo @ 327680
//  W1hi @ 655360   [128][5120]   (k = i*128 + j)
//  W1lo @ 1310720
//  W2hi @ 1966080
//  W2lo @ 2621440            total 3,276,800 ushorts = 6.55 MB
__global__ void prep_weights(const float* __restrict__ W0,
                             const float* __restrict__ W1,
                             const float* __restrict__ W2,
                             unsigned short* __restrict__ ws)
{
  const int total = 327680 + 655360 + 655360;
  for (int e = blockIdx.x * blockDim.x + threadIdx.x; e < total;
       e += gridDim.x * blockDim.x){
    float w; int hi, lo;
    if (e < 327680){
      int h = e / 2560, k = e % 2560;
      int i = k >> 6, j = k & 63;
      w = (j < 40) ? W0[(i*40 + j)*128 + h] : 0.f;   // W0[i][j][h]
      hi = e; lo = 327680 + e;
    } else if (e < 983040){
      int r = e - 327680;
      int h = r / 5120, k = r % 5120;
      w = W1[k*128 + h];
      hi = 655360 + r; lo = 1310720 + r;
    } else {
      int r = e - 983040;
      int h = r / 5120, k = r % 5120;
      w = W2[k*128 + h];
      hi = 1966080 + r; lo = 2621440 + r;
    }
    unsigned short hb = f2bf(w);
    float whf = __uint_as_float((unsigned)hb << 16);
    unsigned short lb = f2bf(w - whf);
    ws[hi] = hb; ws[lo] = lb;
  }
}

// ---------------- main fused kernel ----------------
// block: 512 threads = 8 waves; 256 rows (4 b * 64 d); wave tile 64r x 64c
// LDS: two bf16 planes [256][128], swizzled: idx = row*128 + (col ^ ((row&7)<<3))
// hi plane @ 0, lo plane @ 32768 (ushort units)

template<int J, int KT, bool WB>
__device__ __forceinline__ void run_layer(
    const unsigned short* __restrict__ Whi,   // lo plane at +128*KT
    const float* __restrict__ xg,
    unsigned short* xkU, float* __restrict__ out,
    int layerOff, int blockRow, int tid)
{
  constexpr int NJB = J / 32;
  constexpr int TOT = 40 * NJB;               // k0 = step*32 (since KT = 40*J)
  constexpr size_t WLO = (size_t)128 * KT;
  const int lane = tid & 63;
  const int wv   = tid >> 6;
  const int cgi  = wv & 1, rgi = wv >> 1;
  const int lrow = lane & 15, q = lane >> 4;

  f4v y[4][4];
#pragma unroll
  for (int a = 0; a < 4; a++)
#pragma unroll
    for (int c = 0; c < 4; c++)
      y[a][c] = (f4v){0.f, 0.f, 0.f, 0.f};

  const unsigned short* wp[4];
#pragma unroll
  for (int nt = 0; nt < 4; nt++)
    wp[nt] = Whi + (size_t)(cgi*64 + nt*16 + lrow) * KT + q*8;

  const int b = (blockRow >> 6) + rgi;              // this wave's batch index
  const float* xrow = xg + (size_t)b * 40 * 64;     // x[b][i][d]
  const f4v zero4 = (f4v){0.f, 0.f, 0.f, 0.f};

  // depth-1 register prefetch state for B-fragments
  s8v bh[4], bl[4], nbh[4], nbl[4];
#pragma unroll
  for (int nt = 0; nt < 4; nt++){
    bh[nt] = *(const s8v*)(wp[nt]);
    bl[nt] = *(const s8v*)(wp[nt] + WLO);
  }
  f4v x0s[4];
#pragma unroll
  for (int rt = 0; rt < 4; rt++)
    x0s[rt] = *(const f4v*)(xrow + rt*16 + q*4);

#pragma unroll 1
  for (int i = 0; i < 40; i++){
    // prefetch x0 for next i
    f4v nx0[4];
    const int ni = (i < 39) ? i + 1 : i;
#pragma unroll
    for (int rt = 0; rt < 4; rt++)
      nx0[rt] = *(const f4v*)(xrow + ni*64 + rt*16 + q*4);

#pragma unroll
    for (int jb = 0; jb < NJB; jb++){
      const int s = i*NJB + jb;
      const int nk0 = (s + 1 < TOT) ? (s + 1) * 32 : 0;
      // issue next B-fragment loads (used next step)
#pragma unroll
      for (int nt = 0; nt < 4; nt++){
        nbh[nt] = *(const s8v*)(wp[nt] + nk0);
        nbl[nt] = *(const s8v*)(wp[nt] + WLO + nk0);
      }
      // compute current step
#pragma unroll
      for (int rt = 0; rt < 4; rt++){
        const int row = rgi*64 + rt*16 + lrow;
        const int ci  = row*128 + ((jb*32 + q*8) ^ ((lrow & 7) << 3));
        const s8v ah = *(const s8v*)(xkU + ci);
        const s8v al = *(const s8v*)(xkU + 32768 + ci);
#pragma unroll
        for (int nt = 0; nt < 4; nt++){
          f4v t = __builtin_amdgcn_mfma_f32_16x16x32_bf16(ah, bh[nt], zero4, 0, 0, 0);
          t = __builtin_amdgcn_mfma_f32_16x16x32_bf16(ah, bl[nt], t, 0, 0, 0);
          t = __builtin_amdgcn_mfma_f32_16x16x32_bf16(al, bh[nt], t, 0, 0, 0);
          y[rt][nt] += x0s[rt] * t;     // exact f32, per (i,jb) partial
        }
      }
      // rotate prefetch
#pragma unroll
      for (int nt = 0; nt < 4; nt++){ bh[nt] = nbh[nt]; bl[nt] = nbl[nt]; }
    }
#pragma unroll
    for (int rt = 0; rt < 4; rt++) x0s[rt] = nx0[rt];
  }

  // ---- pool over d from registers: wave owns all 64 rows of batch b,
  //      cols cgi*64 + nt*16 + lrow (exclusive across waves) ----
  float ps[4];
#pragma unroll
  for (int nt = 0; nt < 4; nt++){
    float ssum = 0.f;
#pragma unroll
    for (int rt = 0; rt < 4; rt++)
#pragma unroll
      for (int r = 0; r < 4; r++)
        ssum += y[rt][nt][r];
    ssum += __shfl_xor(ssum, 16);
    ssum += __shfl_xor(ssum, 32);
    ps[nt] = ssum;
  }
  if (q == 0){
#pragma unroll
    for (int nt = 0; nt < 4; nt++)
      out[(size_t)b*384 + layerOff + cgi*64 + nt*16 + lrow] = ps[nt];
  }

  __syncthreads();              // all waves done READING old xk planes
  if (WB){
    // write y as new xk hi/lo planes. C/D layout: col=lane&15(=lrow), row=q*4+r
#pragma unroll
    for (int rt = 0; rt < 4; rt++){
#pragma unroll
      for (int nt = 0; nt < 4; nt++){
        const int col = cgi*64 + nt*16 + lrow;
#pragma unroll
        for (int r = 0; r < 4; r++){
          const int row = rgi*64 + rt*16 + q*4 + r;
          const float v = y[rt][nt][r];
          unsigned short hb = f2bf(v);
          unsigned short lb = f2bf(v - __uint_as_float((unsigned)hb << 16));
          const int pi = row*128 + (col ^ ((row & 7) << 3));
          xkU[pi] = hb;
          xkU[32768 + pi] = lb;
        }
      }
    }
    __syncthreads();            // new planes visible
  }
}

__global__ __launch_bounds__(512, 2) void cin_main(
    const float* __restrict__ xg,
    const unsigned short* __restrict__ wsbase,
    float* __restrict__ out)
{
  extern __shared__ unsigned short xkU[];   // 2 planes x [256][128] bf16 = 128 KiB
  const int tid = threadIdx.x;
  const int blockRow = blockIdx.x * 256;

  // stage layer-1 xk = x (cols j<40 real, pad to 64; cols 64..127 unused)
#pragma unroll 1
  for (int it = 0; it < 32; it++){
    int idx = it*512 + tid;
    int row = idx & 255, j = idx >> 8;      // j in [0,64)
    float v = 0.f;
    if (j < 40){
      int bb = (blockRow >> 6) + (row >> 6);
      v = xg[((size_t)bb*40 + j)*64 + (row & 63)];
    }
    unsigned short hb = f2bf(v);
    unsigned short lb = f2bf(v - __uint_as_float((unsigned)hb << 16));
    const int pi = row*128 + (j ^ ((row & 7) << 3));
    xkU[pi] = hb;
    xkU[32768 + pi] = lb;
  }
  __syncthreads();

  run_layer< 64, 2560, true >(wsbase,           xg, xkU, out,   0, blockRow, tid);
  run_layer<128, 5120, true >(wsbase + 655360,  xg, xkU, out, 128, blockRow, tid);
  run_layer<128, 5120, false>(wsbase + 1966080, xg, xkU, out, 256, blockRow, tid);
}

extern "C" void kernel_launch(void* const* d_in, const int* in_sizes, int n_in,
                              void* d_out, int out_size, void* d_ws, size_t ws_size,
                              hipStream_t stream)
{
  (void)in_sizes; (void)n_in; (void)out_size; (void)ws_size;
  const float* x  = (const float*)d_in[0];
  const float* W0 = (const float*)d_in[1];
  const float* W1 = (const float*)d_in[2];
  const float* W2 = (const float*)d_in[3];
  float* out = (float*)d_out;
  unsigned short* ws = (unsigned short*)d_ws;   // needs 6,553,600 bytes

  hipFuncSetAttribute((const void*)cin_main,
                      hipFuncAttributeMaxDynamicSharedMemorySize, 131072);

  prep_weights<<<2048, 256, 0, stream>>>(W0, W1, W2, ws);
  cin_main<<<256, 512, 131072, stream>>>(x, ws, out);
}

// Round 6
// 1068.683 us; speedup vs baseline: 1.2977x; 1.2977x over previous
//
#include <hip/hip_runtime.h>
#include <cstdint>
#include <cstddef>

// CIN: B=1024, M=40, D=64, HK=128. rows = B*D = 65536 (row = b*64 + d)
// y[r,h] = sum_i x0[r,i] * ( sum_j xk[r,j] * W[i,j,h] )
// Inner j-contraction via bf16 MFMA (xk split hi/lo once per layer in LDS);
// x0 applied per (i,jb) PARTIAL in exact f32 (linearity) -> no cross-jb t regs.
// 3-term split: xk*w ~= xkh*wh + xkh*wl + xkl*wh  (error ~2^-18 rel)
// ROUND 6: no hand-rolled prefetch (round 3/5 showed it re-creates the spill);
// compiler schedules B-loads within the ~80-reg headroom.

typedef __attribute__((ext_vector_type(4))) float f4v;
typedef __attribute__((ext_vector_type(8))) short s8v;

__device__ __forceinline__ unsigned short f2bf(float f){
  unsigned u = __float_as_uint(f);
  u += 0x7fffu + ((u >> 16) & 1u);      // RNE on bf16 boundary
  return (unsigned short)(u >> 16);
}

// ---------------- weight prep: split + transpose into ws ----------------
// ws layout (ushort units):
//  W0hi @ 0        [128][2560]   (k = i*64 + j, j<40 real else 0)
//  W0lo @ 327680
//  W1hi @ 655360   [128][5120]   (k = i*128 + j)
//  W1lo @ 1310720
//  W2hi @ 1966080
//  W2lo @ 2621440            total 3,276,800 ushorts = 6.55 MB
__global__ void prep_weights(const float* __restrict__ W0,
                             const float* __restrict__ W1,
                             const float* __restrict__ W2,
                             unsigned short* __restrict__ ws)
{
  const int total = 327680 + 655360 + 655360;
  for (int e = blockIdx.x * blockDim.x + threadIdx.x; e < total;
       e += gridDim.x * blockDim.x){
    float w; int hi, lo;
    if (e < 327680){
      int h = e / 2560, k = e % 2560;
      int i = k >> 6, j = k & 63;
      w = (j < 40) ? W0[(i*40 + j)*128 + h] : 0.f;   // W0[i][j][h]
      hi = e; lo = 327680 + e;
    } else if (e < 983040){
      int r = e - 327680;
      int h = r / 5120, k = r % 5120;
      w = W1[k*128 + h];
      hi = 655360 + r; lo = 1310720 + r;
    } else {
      int r = e - 983040;
      int h = r / 5120, k = r % 5120;
      w = W2[k*128 + h];
      hi = 1966080 + r; lo = 2621440 + r;
    }
    unsigned short hb = f2bf(w);
    float whf = __uint_as_float((unsigned)hb << 16);
    unsigned short lb = f2bf(w - whf);
    ws[hi] = hb; ws[lo] = lb;
  }
}

// ---------------- main fused kernel ----------------
// block: 512 threads = 8 waves; 256 rows (4 b * 64 d); wave tile 64r x 64c
// LDS: two bf16 planes [256][128], swizzled: idx = row*128 + (col ^ ((row&7)<<3))
// hi plane @ 0, lo plane @ 32768 (ushort units)

template<int J, int KT, bool WB>
__device__ __forceinline__ void run_layer(
    const unsigned short* __restrict__ Whi,   // lo plane at +128*KT
    const float* __restrict__ xg,
    unsigned short* xkU, float* __restrict__ out,
    int layerOff, int blockRow, int tid)
{
  constexpr int NJB = J / 32;
  constexpr size_t WLO = (size_t)128 * KT;
  const int lane = tid & 63;
  const int wv   = tid >> 6;
  const int cgi  = wv & 1, rgi = wv >> 1;
  const int lrow = lane & 15, q = lane >> 4;

  f4v y[4][4];
#pragma unroll
  for (int a = 0; a < 4; a++)
#pragma unroll
    for (int c = 0; c < 4; c++)
      y[a][c] = (f4v){0.f, 0.f, 0.f, 0.f};

  const unsigned short* wp[4];
#pragma unroll
  for (int nt = 0; nt < 4; nt++)
    wp[nt] = Whi + (size_t)(cgi*64 + nt*16 + lrow) * KT + q*8;

  const int b = (blockRow >> 6) + rgi;              // this wave's batch index
  const float* xrow = xg + (size_t)b * 40 * 64;     // x[b][i][d]
  const f4v zero4 = (f4v){0.f, 0.f, 0.f, 0.f};

#pragma unroll 1
  for (int i = 0; i < 40; i++){
    f4v x0s[4];
#pragma unroll
    for (int rt = 0; rt < 4; rt++)
      x0s[rt] = *(const f4v*)(xrow + i*64 + rt*16 + q*4);

#pragma unroll
    for (int jb = 0; jb < NJB; jb++){
      const int k0 = i*J + jb*32;
      s8v bh[4], bl[4];
#pragma unroll
      for (int nt = 0; nt < 4; nt++){
        bh[nt] = *(const s8v*)(wp[nt] + k0);
        bl[nt] = *(const s8v*)(wp[nt] + WLO + k0);
      }
#pragma unroll
      for (int rt = 0; rt < 4; rt++){
        const int row = rgi*64 + rt*16 + lrow;
        const int ci  = row*128 + ((jb*32 + q*8) ^ ((lrow & 7) << 3));
        const s8v ah = *(const s8v*)(xkU + ci);
        const s8v al = *(const s8v*)(xkU + 32768 + ci);
#pragma unroll
        for (int nt = 0; nt < 4; nt++){
          f4v t = __builtin_amdgcn_mfma_f32_16x16x32_bf16(ah, bh[nt], zero4, 0, 0, 0);
          t = __builtin_amdgcn_mfma_f32_16x16x32_bf16(ah, bl[nt], t, 0, 0, 0);
          t = __builtin_amdgcn_mfma_f32_16x16x32_bf16(al, bh[nt], t, 0, 0, 0);
          y[rt][nt] += x0s[rt] * t;     // exact f32, per (i,jb) partial
        }
      }
    }
  }

  // ---- pool over d from registers: wave owns all 64 rows of batch b,
  //      cols cgi*64 + nt*16 + lrow (exclusive across waves) ----
  float ps[4];
#pragma unroll
  for (int nt = 0; nt < 4; nt++){
    float ssum = 0.f;
#pragma unroll
    for (int rt = 0; rt < 4; rt++)
#pragma unroll
      for (int r = 0; r < 4; r++)
        ssum += y[rt][nt][r];
    ssum += __shfl_xor(ssum, 16);
    ssum += __shfl_xor(ssum, 32);
    ps[nt] = ssum;
  }
  if (q == 0){
#pragma unroll
    for (int nt = 0; nt < 4; nt++)
      out[(size_t)b*384 + layerOff + cgi*64 + nt*16 + lrow] = ps[nt];
  }

  __syncthreads();              // all waves done READING old xk planes
  if (WB){
    // write y as new xk hi/lo planes. C/D layout: col=lane&15(=lrow), row=q*4+r
#pragma unroll
    for (int rt = 0; rt < 4; rt++){
#pragma unroll
      for (int nt = 0; nt < 4; nt++){
        const int col = cgi*64 + nt*16 + lrow;
#pragma unroll
        for (int r = 0; r < 4; r++){
          const int row = rgi*64 + rt*16 + q*4 + r;
          const float v = y[rt][nt][r];
          unsigned short hb = f2bf(v);
          unsigned short lb = f2bf(v - __uint_as_float((unsigned)hb << 16));
          const int pi = row*128 + (col ^ ((row & 7) << 3));
          xkU[pi] = hb;
          xkU[32768 + pi] = lb;
        }
      }
    }
    __syncthreads();            // new planes visible
  }
}

__global__ __launch_bounds__(512, 2) void cin_main(
    const float* __restrict__ xg,
    const unsigned short* __restrict__ wsbase,
    float* __restrict__ out)
{
  extern __shared__ unsigned short xkU[];   // 2 planes x [256][128] bf16 = 128 KiB
  const int tid = threadIdx.x;
  const int blockRow = blockIdx.x * 256;

  // stage layer-1 xk = x (cols j<40 real, pad to 64; cols 64..127 unused)
#pragma unroll 1
  for (int it = 0; it < 32; it++){
    int idx = it*512 + tid;
    int row = idx & 255, j = idx >> 8;      // j in [0,64)
    float v = 0.f;
    if (j < 40){
      int bb = (blockRow >> 6) + (row >> 6);
      v = xg[((size_t)bb*40 + j)*64 + (row & 63)];
    }
    unsigned short hb = f2bf(v);
    unsigned short lb = f2bf(v - __uint_as_float((unsigned)hb << 16));
    const int pi = row*128 + (j ^ ((row & 7) << 3));
    xkU[pi] = hb;
    xkU[32768 + pi] = lb;
  }
  __syncthreads();

  run_layer< 64, 2560, true >(wsbase,           xg, xkU, out,   0, blockRow, tid);
  run_layer<128, 5120, true >(wsbase + 655360,  xg, xkU, out, 128, blockRow, tid);
  run_layer<128, 5120, false>(wsbase + 1966080, xg, xkU, out, 256, blockRow, tid);
}

extern "C" void kernel_launch(void* const* d_in, const int* in_sizes, int n_in,
                              void* d_out, int out_size, void* d_ws, size_t ws_size,
                              hipStream_t stream)
{
  (void)in_sizes; (void)n_in; (void)out_size; (void)ws_size;
  const float* x  = (const float*)d_in[0];
  const float* W0 = (const float*)d_in[1];
  const float* W1 = (const float*)d_in[2];
  const float* W2 = (const float*)d_in[3];
  float* out = (float*)d_out;
  unsigned short* ws = (unsigned short*)d_ws;   // needs 6,553,600 bytes

  hipFuncSetAttribute((const void*)cin_main,
                      hipFuncAttributeMaxDynamicSharedMemorySize, 131072);

  prep_weights<<<2048, 256, 0, stream>>>(W0, W1, W2, ws);
  cin_main<<<256, 512, 131072, stream>>>(x, ws, out);
}